// Round 16
// baseline (337.281 us; speedup 1.0000x reference)
//
#include <hip/hip_runtime.h>
#include <hip/hip_fp16.h>

// ---------------------------------------------------------------------------
// 2-layer GCN (PyG GCNConv): deg^{-1/2} sym norm with self-loops.
// Round 16 = round 15 with ds_swizzle patterns made compile-time literals
// (hand-unrolled macro; builtin requires a constant-integer pattern).
//   - Gathers: 16 nodes x 4 lanes x 8 B/lane. Per 8-edge batch: 2 index
//     loads (prefetched a batch ahead), 8 ds_swizzle immediate broadcasts
//     (group-internal, no addr VGPR), 8 x 8B unconditional loads, 32 fdot2.
//   - Dummy-padded CSR (pad to x8, dummy index N -> zeroed payload row);
//     fdot2 fp32 accumulate; within-chunk degree sort (locality-neutral).
//   - xhT[8][N+1][16] fp16 slices (3.2 MB -> one XCD L2, blockIdx&7 -> XCD).
//   - aggT slice-major [8][N][16]; mgemm1 reads it directly (TIN).
//   - thT [4][N+1][16]; gatherT64 writes row-major out (+b2), float4/lane.
// ---------------------------------------------------------------------------

#define NT 256

typedef _Float16 half8 __attribute__((ext_vector_type(8)));
typedef _Float16 h2 __attribute__((ext_vector_type(2)));
typedef _Float16 h4 __attribute__((ext_vector_type(4)));
typedef float floatx4 __attribute__((ext_vector_type(4)));

#if __has_builtin(__builtin_amdgcn_fdot2)
__device__ __forceinline__ float dot2f(h2 a, h2 b, float c) {
    return __builtin_amdgcn_fdot2(a, b, c, false);
}
#else
__device__ __forceinline__ float dot2f(h2 a, h2 b, float c) {
    return c + (float)a.x * (float)b.x + (float)a.y * (float)b.y;
}
#endif

// ---------------- init: zero counts, fill srcs with dummy ----------
__global__ void init_k(int* __restrict__ cnt, int* __restrict__ srcs, int n, int m) {
    int i = blockIdx.x * NT + threadIdx.x;
    if (i < n) cnt[i] = 0;
    if (i < m) srcs[i] = n;  // dummy index -> zeroed payload row
}

__global__ void deg_count_k(const int* __restrict__ dst, int* __restrict__ c, int e) {
    int i = blockIdx.x * NT + threadIdx.x;
    if (i < e) atomicAdd(&c[dst[i]], 1);
}

// exclusive scan of PADDED counts -> rowptr; emits dinv, pdeg
__global__ void scan1_k(const int* __restrict__ counts, int* __restrict__ rowptr,
                        int* __restrict__ bsum, float* __restrict__ dinv,
                        int* __restrict__ pdeg, int n) {
    __shared__ int s[NT];
    int tid = threadIdx.x, i = blockIdx.x * NT + tid;
    int v = (i < n) ? counts[i] : 0;
    int pv = (v + 7) & ~7;
    if (i < n) {
        dinv[i] = rsqrtf((float)(v + 1));  // +1 self-loop
        pdeg[i] = pv;
    }
    s[tid] = pv;
    __syncthreads();
    for (int off = 1; off < NT; off <<= 1) {
        int t = (tid >= off) ? s[tid - off] : 0;
        __syncthreads();
        if (tid >= off) s[tid] += t;
        __syncthreads();
    }
    if (i < n) rowptr[i] = s[tid] - pv;
    if (tid == NT - 1) bsum[blockIdx.x] = s[tid];
}

__global__ void scan2_k(int* __restrict__ bsum, int nb) {
    __shared__ int s[512];
    __shared__ int carry;
    int tid = threadIdx.x;
    if (tid == 0) carry = 0;
    __syncthreads();
    for (int base = 0; base < nb; base += 512) {
        int i = base + tid;
        int v = (i < nb) ? bsum[i] : 0;
        s[tid] = v;
        __syncthreads();
        for (int off = 1; off < 512; off <<= 1) {
            int t = (tid >= off) ? s[tid - off] : 0;
            __syncthreads();
            if (tid >= off) s[tid] += t;
            __syncthreads();
        }
        int tot = s[511];
        if (i < nb) bsum[i] = s[tid] - v + carry;
        __syncthreads();
        if (tid == 0) carry += tot;
        __syncthreads();
    }
}

__global__ void scan3_k(int* __restrict__ rowptr, const int* __restrict__ bsum,
                        int* __restrict__ cursor, int n) {
    int i = blockIdx.x * NT + threadIdx.x;
    if (i < n) {
        int r = rowptr[i] + bsum[i / NT];
        rowptr[i] = r;
        cursor[i] = r;
    }
}

// ---------------- within-chunk degree sort (32-node chunks) ----------------
__global__ void csort_k(const int* __restrict__ pdeg, int* __restrict__ perm, int n) {
    __shared__ int key[NT], val[NT];
    int tid = threadIdx.x;
    int i = blockIdx.x * NT + tid;
    key[tid] = (i < n) ? pdeg[i] : 0x7fffffff;
    val[tid] = i;
    __syncthreads();
    int lid = tid & 31, cb = tid & ~31;
    for (int k = 2; k <= 32; k <<= 1) {
        for (int j = k >> 1; j > 0; j >>= 1) {
            int ixj = lid ^ j;
            if (ixj > lid) {
                bool up = ((lid & k) == 0);
                int ka = key[cb + lid], kb = key[cb + ixj];
                if ((ka > kb) == up) {
                    int va = val[cb + lid], vb = val[cb + ixj];
                    key[cb + lid] = kb; key[cb + ixj] = ka;
                    val[cb + lid] = vb; val[cb + ixj] = va;
                }
            }
            __syncthreads();
        }
    }
    if (i < n) perm[i] = val[tid];
}

// XCD-localized scatter (round 5)
__global__ __launch_bounds__(NT) void scatter_xcd_k(
    const int* __restrict__ src, const int* __restrict__ dst,
    int* __restrict__ cursor, int* __restrict__ srcs,
    int e, int rpx, int csz) {
    int q  = blockIdx.x & 7;
    int ch = blockIdx.x >> 3;
    int lo = q * rpx, hi = lo + rpx;
    int e0 = ch * csz;
    int e1 = min(e, e0 + csz);
    for (int i = e0 + (int)threadIdx.x; i < e1; i += NT) {
        int d = dst[i];
        if (d >= lo && d < hi) {
            int pos = atomicAdd(&cursor[d], 1);
            srcs[pos] = src[i];
        }
    }
}

// ---------------- conv1T: x -> xhT[8][N+1][16] fp16 (row N zeroed) ---------
__global__ void conv1T_k(const float* __restrict__ x, const float* __restrict__ dinv,
                         __half* __restrict__ xhT, int n) {
    int t = blockIdx.x * NT + threadIdx.x;
    int node = t >> 3;
    if (node > n) return;
    int q = t & 7;
    int4 o0, o1;
    if (node == n) {
        o0 = make_int4(0, 0, 0, 0);
        o1 = o0;
    } else {
        float dn = dinv[node];
        const float4* xp =
            reinterpret_cast<const float4*>(x + (size_t)node * 128 + q * 16);
        __half2 h[8];
#pragma unroll
        for (int j = 0; j < 4; ++j) {
            float4 a = xp[j];
            h[2 * j + 0] = __floats2half2_rn(a.x * dn, a.y * dn);
            h[2 * j + 1] = __floats2half2_rn(a.z * dn, a.w * dn);
        }
        o0 = reinterpret_cast<int4*>(h)[0];
        o1 = reinterpret_cast<int4*>(h)[1];
    }
    int4* op = reinterpret_cast<int4*>(xhT + ((size_t)q * (n + 1) + node) * 16);
    op[0] = o0;
    op[1] = o1;
}

// zero thT's dummy rows; run after mgemm1 (overlays aggT), before mgemm2
__global__ void zero_thT_k(__half* __restrict__ thT, int n) {
    int t = threadIdx.x;  // 64 threads
    int sl = t >> 4, j = t & 15;
    thT[((size_t)sl * (n + 1) + n) * 16 + j] = __float2half(0.0f);
}

// ---------------- sliced gathers, 16 nodes x 4 lanes per wave ---------------
// Payload: [slice][N+1][16] fp16 -> 32 B/node/slice; row N zeros. Lane owns
// 8 B (4 cols). ds_swizzle BitMode broadcast within 4-lane group:
// lane' = (lane & 0x1C) | u  ->  offset imm = (u << 5) | 0x1C (literal).

#define GSTEP(sreg, uu)                                                      \
    {                                                                        \
        int s_ = __builtin_amdgcn_ds_swizzle((sreg), ((uu) << 5) | 0x1C);    \
        h4 f_ = *(const h4*)(base + (unsigned)s_ * 32u + c8);                \
        h2 flo_ = __builtin_shufflevector(f_, f_, 0, 1);                     \
        h2 fhi_ = __builtin_shufflevector(f_, f_, 2, 3);                     \
        a0 = dot2f(flo_, b10, a0);                                           \
        a1 = dot2f(flo_, b01, a1);                                           \
        a2 = dot2f(fhi_, b10, a2);                                           \
        a3 = dot2f(fhi_, b01, a3);                                           \
    }

__global__ __launch_bounds__(NT) void gatherT128_k(
    const int* __restrict__ rowptr, const int* __restrict__ pdeg,
    const int* __restrict__ perm, const int* __restrict__ srcs,
    const float* __restrict__ dinv, const __half* __restrict__ xhT,
    __half* __restrict__ aggT, int n) {
    const int slice = blockIdx.x & 7;
    const int chunk = blockIdx.x >> 3;
    const int lane  = threadIdx.x & 63;
    const int wid   = threadIdx.x >> 6;
    const int g     = lane >> 2;   // node sub-group 0..15
    const int c     = lane & 3;    // 8B sub-column / srcs sub-index
    const int idx   = chunk * 64 + wid * 16 + g;
    if (idx >= n) return;  // 4-lane groups exit together (idx indep. of c)
    const int node = perm[idx];   // within idx's own 32-chunk

    const int e0 = rowptr[node];
    const int pd = pdeg[node];
    const char* base = (const char*)(xhT + (size_t)slice * (n + 1) * 16);
    const unsigned c8 = (unsigned)c * 8u;
    const h2 b10 = {(_Float16)1.0f, (_Float16)0.0f};
    const h2 b01 = {(_Float16)0.0f, (_Float16)1.0f};

    // self-loop (8 B = 4 cols)
    h4 fs = *(const h4*)(base + (size_t)node * 32 + c8);
    h2 lo = __builtin_shufflevector(fs, fs, 0, 1);
    h2 hi = __builtin_shufflevector(fs, fs, 2, 3);
    float a0 = dot2f(lo, b10, 0.0f), a1 = dot2f(lo, b01, 0.0f);
    float a2 = dot2f(hi, b10, 0.0f), a3 = dot2f(hi, b01, 0.0f);

    int sA = srcs[e0 + c];        // batch-0 indices, u = 0..3
    int sB = srcs[e0 + 4 + c];    // u = 4..7
    for (int jb = 0; jb < pd; jb += 8) {
        int nA = srcs[e0 + jb + 8 + c];   // unconditional: buffer padded
        int nB = srcs[e0 + jb + 12 + c];
        GSTEP(sA, 0) GSTEP(sA, 1) GSTEP(sA, 2) GSTEP(sA, 3)
        GSTEP(sB, 0) GSTEP(sB, 1) GSTEP(sB, 2) GSTEP(sB, 3)
        sA = nA; sB = nB;
    }

    float dn = dinv[node];
    __half2 o01 = __floats2half2_rn(a0 * dn, a1 * dn);
    __half2 o23 = __floats2half2_rn(a2 * dn, a3 * dn);
    int2 ov = make_int2(*reinterpret_cast<int*>(&o01), *reinterpret_cast<int*>(&o23));
    *reinterpret_cast<int2*>((char*)aggT + ((size_t)slice * n + node) * 32 + c8) = ov;
}

// gatherT64: 4 slices of 16 cols; q8 -> (slice = q8>>1, node-half = q8&1).
// Writes row-major fp32 out (+b2): lane writes float4; 4 lanes = one 64B line.
__global__ __launch_bounds__(NT) void gatherT64_k(
    const int* __restrict__ rowptr, const int* __restrict__ pdeg,
    const int* __restrict__ perm, const int* __restrict__ srcs,
    const float* __restrict__ dinv, const __half* __restrict__ thT,
    const float* __restrict__ b2, float* __restrict__ out, int n) {
    const int q8    = blockIdx.x & 7;
    const int slice = q8 >> 1;
    const int chunk = blockIdx.x >> 3;
    const int lane  = threadIdx.x & 63;
    const int wid   = threadIdx.x >> 6;
    const int g     = lane >> 2;
    const int c     = lane & 3;
    const int idx   = chunk * 128 + (q8 & 1) * 64 + wid * 16 + g;
    if (idx >= n) return;
    const int node = perm[idx];   // window offsets are 16-aligned in 32-chunks

    const int e0 = rowptr[node];
    const int pd = pdeg[node];
    const char* base = (const char*)(thT + (size_t)slice * (n + 1) * 16);
    const unsigned c8 = (unsigned)c * 8u;
    const h2 b10 = {(_Float16)1.0f, (_Float16)0.0f};
    const h2 b01 = {(_Float16)0.0f, (_Float16)1.0f};

    h4 fs = *(const h4*)(base + (size_t)node * 32 + c8);
    h2 lo = __builtin_shufflevector(fs, fs, 0, 1);
    h2 hi = __builtin_shufflevector(fs, fs, 2, 3);
    float a0 = dot2f(lo, b10, 0.0f), a1 = dot2f(lo, b01, 0.0f);
    float a2 = dot2f(hi, b10, 0.0f), a3 = dot2f(hi, b01, 0.0f);

    int sA = srcs[e0 + c];
    int sB = srcs[e0 + 4 + c];
    for (int jb = 0; jb < pd; jb += 8) {
        int nA = srcs[e0 + jb + 8 + c];
        int nB = srcs[e0 + jb + 12 + c];
        GSTEP(sA, 0) GSTEP(sA, 1) GSTEP(sA, 2) GSTEP(sA, 3)
        GSTEP(sB, 0) GSTEP(sB, 1) GSTEP(sB, 2) GSTEP(sB, 3)
        sA = nA; sB = nB;
    }

    float dn = dinv[node];
    int col = slice * 16 + c * 4;
    *reinterpret_cast<float4*>(&out[(size_t)node * 64 + col]) =
        make_float4(a0 * dn + b2[col + 0], a1 * dn + b2[col + 1],
                    a2 * dn + b2[col + 2], a3 * dn + b2[col + 3]);
}

// ---------------- MFMA fp16 GEMM, register-resident B ----------------
// TIN=true : A is slice-major [8][nrows][16] fp16 (aggT, stride nrows).
// TOUT=true: out slice-major [OC/16][orows][16] fp16 (thT, stride orows).
template <int OC, bool RELU, bool BIAS, bool SCALE_DINV, bool TIN, bool TOUT>
__global__ __launch_bounds__(NT) void mgemm_k(
    const __half* __restrict__ A, const float* __restrict__ W,
    const float* __restrict__ bias, const float* __restrict__ dinv,
    __half* __restrict__ out, int nrows, int orows) {
    constexpr int NREP = OC / 64;  // 2 for OC=128, 1 for OC=64

    const int wid  = threadIdx.x >> 6;
    const int lane = threadIdx.x & 63;
    const int lrow = lane & 15;
    const int kgrp = lane >> 4;
    const int nbase = wid * 16 * NREP;

    // B fragments (loaded once, stay in VGPRs)
    half8 bf[NREP][4];
    float bv[NREP];
#pragma unroll
    for (int nt = 0; nt < NREP; ++nt) {
        int col = nbase + nt * 16 + lrow;
#pragma unroll
        for (int kk = 0; kk < 4; ++kk) {
#pragma unroll
            for (int j = 0; j < 8; ++j) {
                int k = kk * 32 + kgrp * 8 + j;
                bf[nt][kk][j] = (_Float16)W[(size_t)k * OC + col];
            }
        }
        bv[nt] = BIAS ? bias[col] : 0.0f;
    }

    const int m0 = blockIdx.x * 64;

    floatx4 acc[4][NREP];
#pragma unroll
    for (int mt = 0; mt < 4; ++mt)
#pragma unroll
        for (int nt = 0; nt < NREP; ++nt)
            acc[mt][nt] = floatx4{0.f, 0.f, 0.f, 0.f};

#pragma unroll
    for (int kk = 0; kk < 4; ++kk) {
        const int k0 = kk * 32 + kgrp * 8;
        half8 af[4];
#pragma unroll
        for (int mt = 0; mt < 4; ++mt) {
            int row = m0 + mt * 16 + lrow;
            if (row >= nrows) row = nrows - 1;  // clamp; stores guarded
            af[mt] = TIN
                ? *reinterpret_cast<const half8*>(
                      &A[(((size_t)(k0 >> 4)) * nrows + row) * 16 + (k0 & 15)])
                : *reinterpret_cast<const half8*>(&A[(size_t)row * 128 + k0]);
        }
#pragma unroll
        for (int mt = 0; mt < 4; ++mt)
#pragma unroll
            for (int nt = 0; nt < NREP; ++nt)
                acc[mt][nt] = __builtin_amdgcn_mfma_f32_16x16x32_f16(
                    af[mt], bf[nt][kk], acc[mt][nt], 0, 0, 0);
    }

#pragma unroll
    for (int mt = 0; mt < 4; ++mt) {
#pragma unroll
        for (int r = 0; r < 4; ++r) {
            int row = m0 + mt * 16 + kgrp * 4 + r;
            if (row < nrows) {
                float dn = SCALE_DINV ? dinv[row] : 1.0f;
#pragma unroll
                for (int nt = 0; nt < NREP; ++nt) {
                    float v = acc[mt][nt][r];
                    if (BIAS) v += bv[nt];
                    if (RELU) v = fmaxf(v, 0.0f);
                    if (SCALE_DINV) v *= dn;
                    int col = nbase + nt * 16 + lrow;
                    if (TOUT)
                        out[((size_t)(col >> 4) * orows + row) * 16 + (col & 15)] =
                            __float2half(v);
                    else
                        out[(size_t)row * OC + col] = __float2half(v);
                }
            }
        }
    }
}

// ---------------------------------------------------------------------------

extern "C" void kernel_launch(void* const* d_in, const int* in_sizes, int n_in,
                              void* d_out, int out_size, void* d_ws, size_t ws_size,
                              hipStream_t stream) {
    const float* x   = (const float*)d_in[0];
    const int*   ei  = (const int*)d_in[1];
    const float* W1  = (const float*)d_in[2];
    const float* b1  = (const float*)d_in[3];
    const float* W2  = (const float*)d_in[4];
    const float* b2  = (const float*)d_in[5];
    float*       out = (float*)d_out;

    const int N = in_sizes[0] / 128;
    const int E = in_sizes[1] / 2;
    const int* srcp = ei;      // edge_index[0]
    const int* dstp = ei + E;  // edge_index[1]

    const int nb   = (N + NT - 1) / NT;
    const int EPAD = E + 8 * N;  // >= sum(padded degrees) + prefetch slack

    // workspace (512B-aligned):
    //   dinv[N] | cnt[N] | pdeg[N] | rowptr[N] | bsum[nb] | perm[N] | srcs[EPAD]
    //   | regA: xhT[8][N+1][16] fp16, then h1[N][128] fp16
    //   | regB: aggT[8][N][16] fp16, then thT[4][N+1][16] fp16
    char* ws = (char*)d_ws;
    size_t off = 0;
    auto alloc = [&](size_t bytes) {
        char* p = ws + off;
        off = (off + bytes + 511) & ~(size_t)511;
        return p;
    };
    float*  dinv   = (float*)alloc((size_t)N * 4);
    int*    cnt    = (int*)alloc((size_t)N * 4);   // counts, then scatter cursor
    int*    pdeg   = (int*)alloc((size_t)N * 4);
    int*    rowptr = (int*)alloc((size_t)N * 4);
    int*    bsum   = (int*)alloc((size_t)nb * 4);
    int*    perm   = (int*)alloc((size_t)N * 4);
    int*    srcs   = (int*)alloc((size_t)EPAD * 4);
    __half* regA   = (__half*)alloc((size_t)(N + 1) * 128 * 2);
    __half* regB   = (__half*)alloc((size_t)(N + 1) * 128 * 2);

    // ---- padded CSR build + norm + within-chunk degree sort ----
    const int mi = (EPAD > N) ? EPAD : N;
    init_k<<<(mi + NT - 1) / NT, NT, 0, stream>>>(cnt, srcs, N, EPAD);
    deg_count_k<<<(E + NT - 1) / NT, NT, 0, stream>>>(dstp, cnt, E);
    scan1_k<<<nb, NT, 0, stream>>>(cnt, rowptr, bsum, dinv, pdeg, N);
    csort_k<<<nb, NT, 0, stream>>>(pdeg, perm, N);
    scan2_k<<<1, 512, 0, stream>>>(bsum, nb);
    scan3_k<<<nb, NT, 0, stream>>>(rowptr, bsum, cnt, N);
    {
        const int CH  = 2048;
        const int csz = (E + CH - 1) / CH;
        const int rpx = (N + 7) / 8;
        scatter_xcd_k<<<8 * CH, NT, 0, stream>>>(srcp, dstp, cnt, srcs, E, rpx, csz);
    }

    // ---- layer 1: xhT (padded, dummy row zeroed) -> aggT -> h1 ----
    conv1T_k<<<((N + 1) * 8 + NT - 1) / NT, NT, 0, stream>>>(x, dinv, regA, N);
    gatherT128_k<<<((N + 63) / 64) * 8, NT, 0, stream>>>(
        rowptr, pdeg, perm, srcs, dinv, regA, regB, N);
    __half* h1 = regA;  // overlays xhT (dead)
    mgemm_k<128, true, true, false, true, false><<<(N + 63) / 64, NT, 0, stream>>>(
        regB, W1, b1, nullptr, h1, N, N);

    // ---- layer 2: thT = (h1 @ W2)*dinv (slice-major, padded) -> out ----
    __half* thT = regB;  // overlays aggT (dead)
    zero_thT_k<<<1, 64, 0, stream>>>(thT, N);
    mgemm_k<64, false, false, true, false, true><<<(N + 63) / 64, NT, 0, stream>>>(
        h1, W2, nullptr, dinv, thT, N, N + 1);
    gatherT64_k<<<((N + 127) / 128) * 8, NT, 0, stream>>>(
        rowptr, pdeg, perm, srcs, dinv, thT, b2, out, N);
}

// Round 17
// 308.723 us; speedup vs baseline: 1.0925x; 1.0925x over previous
//
#include <hip/hip_runtime.h>
#include <hip/hip_fp16.h>

// ---------------------------------------------------------------------------
// 2-layer GCN (PyG GCNConv): deg^{-1/2} sym norm with self-loops.
// Round 17 = round 11 gathers (best measured: 74.7us) + fused MLP + lean prep.
//   - mgemm_fused: aggT -(MFMA W1 +b1,relu)-> LDS h1 tile -(MFMA W2,*dinv)->
//     thT. Kills the 51 MB h1 global round-trip and 2 launches.
//   - Precise pad fill (<=7 dummy slots/node) instead of 9.6 MB memset.
//   - Dummy-padded CSR (dummy index N -> zeroed payload row): no masks or
//     ballots in gather loops; fdot2 fp32 accumulate.
//   - xhT[8][N+1][16] fp16 slices (3.2 MB -> one XCD L2, blockIdx&7 -> XCD).
//   - aggT slice-major [8][N][16]; fused GEMM reads it directly.
//   - thT [4][N+1][16] in its own region; gatherT64 writes row-major out(+b2).
// ---------------------------------------------------------------------------

#define NT 256

typedef _Float16 half8 __attribute__((ext_vector_type(8)));
typedef _Float16 h2 __attribute__((ext_vector_type(2)));
typedef float floatx4 __attribute__((ext_vector_type(4)));

#if __has_builtin(__builtin_amdgcn_fdot2)
__device__ __forceinline__ float dot2f(h2 a, h2 b, float c) {
    return __builtin_amdgcn_fdot2(a, b, c, false);
}
#else
__device__ __forceinline__ float dot2f(h2 a, h2 b, float c) {
    return c + (float)a.x * (float)b.x + (float)a.y * (float)b.y;
}
#endif

// ---------------- CSR build ----------------

__global__ void zero_cnt_k(int* __restrict__ cnt, int n) {
    int i = blockIdx.x * NT + threadIdx.x;
    if (i < n) cnt[i] = 0;
}

__global__ void deg_count_k(const int* __restrict__ dst, int* __restrict__ c, int e) {
    int i = blockIdx.x * NT + threadIdx.x;
    if (i < e) atomicAdd(&c[dst[i]], 1);
}

// exclusive scan of PADDED counts -> rowptr; emits dinv, pdeg
__global__ void scan1_k(const int* __restrict__ counts, int* __restrict__ rowptr,
                        int* __restrict__ bsum, float* __restrict__ dinv,
                        int* __restrict__ pdeg, int n) {
    __shared__ int s[NT];
    int tid = threadIdx.x, i = blockIdx.x * NT + tid;
    int v = (i < n) ? counts[i] : 0;
    int pv = (v + 7) & ~7;
    if (i < n) {
        dinv[i] = rsqrtf((float)(v + 1));  // +1 self-loop
        pdeg[i] = pv;
    }
    s[tid] = pv;
    __syncthreads();
    for (int off = 1; off < NT; off <<= 1) {
        int t = (tid >= off) ? s[tid - off] : 0;
        __syncthreads();
        if (tid >= off) s[tid] += t;
        __syncthreads();
    }
    if (i < n) rowptr[i] = s[tid] - pv;
    if (tid == NT - 1) bsum[blockIdx.x] = s[tid];
}

__global__ void scan2_k(int* __restrict__ bsum, int nb) {
    __shared__ int s[512];
    __shared__ int carry;
    int tid = threadIdx.x;
    if (tid == 0) carry = 0;
    __syncthreads();
    for (int base = 0; base < nb; base += 512) {
        int i = base + tid;
        int v = (i < nb) ? bsum[i] : 0;
        s[tid] = v;
        __syncthreads();
        for (int off = 1; off < 512; off <<= 1) {
            int t = (tid >= off) ? s[tid - off] : 0;
            __syncthreads();
            if (tid >= off) s[tid] += t;
            __syncthreads();
        }
        int tot = s[511];
        if (i < nb) bsum[i] = s[tid] - v + carry;
        __syncthreads();
        if (tid == 0) carry += tot;
        __syncthreads();
    }
}

__global__ void scan3_k(int* __restrict__ rowptr, const int* __restrict__ bsum,
                        int* __restrict__ cursor, int n) {
    int i = blockIdx.x * NT + threadIdx.x;
    if (i < n) {
        int r = rowptr[i] + bsum[i / NT];
        rowptr[i] = r;
        cursor[i] = r;
    }
}

// XCD-localized scatter (round 5)
__global__ __launch_bounds__(NT) void scatter_xcd_k(
    const int* __restrict__ src, const int* __restrict__ dst,
    int* __restrict__ cursor, int* __restrict__ srcs,
    int e, int rpx, int csz) {
    int q  = blockIdx.x & 7;
    int ch = blockIdx.x >> 3;
    int lo = q * rpx, hi = lo + rpx;
    int e0 = ch * csz;
    int e1 = min(e, e0 + csz);
    for (int i = e0 + (int)threadIdx.x; i < e1; i += NT) {
        int d = dst[i];
        if (d >= lo && d < hi) {
            int pos = atomicAdd(&cursor[d], 1);
            srcs[pos] = src[i];
        }
    }
}

// precise pad fill: after scatter, cursor[i] = rowptr[i] + real_deg.
// Fill [cursor[i], rowptr[i]+pdeg[i]) with dummy N; last node adds +8 slack
// for the gather's unconditional one-batch-ahead prefetch.
__global__ void fill_pads_k(const int* __restrict__ cursor,
                            const int* __restrict__ rowptr,
                            const int* __restrict__ pdeg,
                            int* __restrict__ srcs, int n) {
    int i = blockIdx.x * NT + threadIdx.x;
    if (i >= n) return;
    int e  = cursor[i];
    int e1 = rowptr[i] + pdeg[i];
    for (; e < e1; ++e) srcs[e] = n;
    if (i == n - 1) {
#pragma unroll
        for (int j = 0; j < 8; ++j) srcs[e1 + j] = n;
    }
}

// ---------------- conv1T: x -> xhT[8][N+1][16] fp16 (row N zeroed) ---------
__global__ void conv1T_k(const float* __restrict__ x, const float* __restrict__ dinv,
                         __half* __restrict__ xhT, int n) {
    int t = blockIdx.x * NT + threadIdx.x;
    int node = t >> 3;
    if (node > n) return;
    int q = t & 7;
    int4 o0, o1;
    if (node == n) {
        o0 = make_int4(0, 0, 0, 0);
        o1 = o0;
    } else {
        float dn = dinv[node];
        const float4* xp =
            reinterpret_cast<const float4*>(x + (size_t)node * 128 + q * 16);
        __half2 h[8];
#pragma unroll
        for (int j = 0; j < 4; ++j) {
            float4 a = xp[j];
            h[2 * j + 0] = __floats2half2_rn(a.x * dn, a.y * dn);
            h[2 * j + 1] = __floats2half2_rn(a.z * dn, a.w * dn);
        }
        o0 = reinterpret_cast<int4*>(h)[0];
        o1 = reinterpret_cast<int4*>(h)[1];
    }
    int4* op = reinterpret_cast<int4*>(xhT + ((size_t)q * (n + 1) + node) * 16);
    op[0] = o0;
    op[1] = o1;
}

// ---------------- sliced gathers, 8 nodes x 8 lanes per wave (r11 form) ----
// Payload: [slice][N+1][16] fp16 -> 32 B per node per slice; row N is zeros.
// Per batch of 8 edges: 1 coalesced srcs load (next batch prefetched
// unconditionally into the padded buffer), 8 shfl broadcasts, 8 unconditional
// 4B loads, 16 fdot2 fp32-accumulates. No masks, no ballots.

__global__ __launch_bounds__(NT) void gatherT128_k(
    const int* __restrict__ rowptr, const int* __restrict__ pdeg,
    const int* __restrict__ srcs, const float* __restrict__ dinv,
    const __half* __restrict__ xhT, __half2* __restrict__ aggT, int n) {
    const int slice = blockIdx.x & 7;
    const int chunk = blockIdx.x >> 3;
    const int lane  = threadIdx.x & 63;
    const int wid   = threadIdx.x >> 6;
    const int g     = lane >> 3;   // node sub-group 0..7
    const int c     = lane & 7;    // half2 col within slice / srcs sub-index
    const int node  = chunk * 32 + wid * 8 + g;
    if (node >= n) return;  // shfl sources stay within each 8-lane group

    const int e0 = rowptr[node];
    const int pd = pdeg[node];
    const char* base = (const char*)(xhT + (size_t)slice * (n + 1) * 16);
    const unsigned c4 = (unsigned)c * 4u;
    const h2 b10 = {(_Float16)1.0f, (_Float16)0.0f};
    const h2 b01 = {(_Float16)0.0f, (_Float16)1.0f};

    // self-loop
    h2 fs = *(const h2*)(base + (size_t)node * 32 + c4);
    float ax = dot2f(fs, b10, 0.0f);
    float ay = dot2f(fs, b01, 0.0f);

    int sidx = srcs[e0 + c];
    for (int jb = 0; jb < pd; jb += 8) {
        int snext = srcs[e0 + jb + 8 + c];  // unconditional: buffer padded
#pragma unroll
        for (int u = 0; u < 8; ++u) {
            int s = __shfl(sidx, (g << 3) | u, 64);
            h2 f = *(const h2*)(base + (unsigned)s * 32u + c4);
            ax = dot2f(f, b10, ax);
            ay = dot2f(f, b01, ay);
        }
        sidx = snext;
    }

    float dn = dinv[node];
    aggT[((size_t)slice * n + node) * 8 + c] = __floats2half2_rn(ax * dn, ay * dn);
}

// gatherT64: 4 slices of 16 cols; q8 -> (slice = q8>>1, node-half = q8&1).
// Writes row-major fp32 out directly (+b2): slice = one 64B line per row.
__global__ __launch_bounds__(NT) void gatherT64_k(
    const int* __restrict__ rowptr, const int* __restrict__ pdeg,
    const int* __restrict__ srcs, const float* __restrict__ dinv,
    const __half* __restrict__ thT, const float* __restrict__ b2,
    float* __restrict__ out, int n) {
    const int q8    = blockIdx.x & 7;
    const int slice = q8 >> 1;
    const int chunk = blockIdx.x >> 3;
    const int lane  = threadIdx.x & 63;
    const int wid   = threadIdx.x >> 6;
    const int g     = lane >> 3;
    const int c     = lane & 7;
    const int node  = chunk * 64 + (q8 & 1) * 32 + wid * 8 + g;
    if (node >= n) return;

    const int e0 = rowptr[node];
    const int pd = pdeg[node];
    const char* base = (const char*)(thT + (size_t)slice * (n + 1) * 16);
    const unsigned c4 = (unsigned)c * 4u;
    const h2 b10 = {(_Float16)1.0f, (_Float16)0.0f};
    const h2 b01 = {(_Float16)0.0f, (_Float16)1.0f};

    h2 fs = *(const h2*)(base + (size_t)node * 32 + c4);
    float ax = dot2f(fs, b10, 0.0f);
    float ay = dot2f(fs, b01, 0.0f);

    int sidx = srcs[e0 + c];
    for (int jb = 0; jb < pd; jb += 8) {
        int snext = srcs[e0 + jb + 8 + c];
#pragma unroll
        for (int u = 0; u < 8; ++u) {
            int s = __shfl(sidx, (g << 3) | u, 64);
            h2 f = *(const h2*)(base + (unsigned)s * 32u + c4);
            ax = dot2f(f, b10, ax);
            ay = dot2f(f, b01, ay);
        }
        sidx = snext;
    }

    float dn = dinv[node];
    int col = slice * 16 + c * 2;
    *reinterpret_cast<float2*>(&out[(size_t)node * 64 + col]) =
        make_float2(ax * dn + b2[col], ay * dn + b2[col + 1]);
}

// ---------------- fused MLP: thT = (relu(aggT@W1 + b1) @ W2) * dinv --------
// MFMA fp16, register-resident W1 (32 cols/wave) and W2 (16 cols/wave).
// h1 64x128 tile staged in LDS ([64][136] fp16: row-stride 68 dwords ->
// 2-way bank aliasing only, free). Block 0 zeros thT's dummy rows (thT is a
// separate ws region, so this cannot race aggT reads).
__global__ __launch_bounds__(NT) void mgemm_fused_k(
    const __half* __restrict__ aggT, const float* __restrict__ W1,
    const float* __restrict__ b1, const float* __restrict__ W2,
    const float* __restrict__ dinv, __half* __restrict__ thT, int n) {
    __shared__ _Float16 h1s[64][136];

    const int wid  = threadIdx.x >> 6;
    const int lane = threadIdx.x & 63;
    const int lrow = lane & 15;
    const int kgrp = lane >> 4;

    if (blockIdx.x == 0 && threadIdx.x < 64) {
        int sl = threadIdx.x >> 4, j = threadIdx.x & 15;
        thT[((size_t)sl * (n + 1) + n) * 16 + j] = __float2half(0.0f);
    }

    // W1 fragments: wave covers cols [wid*32, wid*32+32)
    half8 bf1[2][4];
    float bv[2];
#pragma unroll
    for (int nt = 0; nt < 2; ++nt) {
        int col = wid * 32 + nt * 16 + lrow;
#pragma unroll
        for (int kk = 0; kk < 4; ++kk)
#pragma unroll
            for (int j = 0; j < 8; ++j)
                bf1[nt][kk][j] = (_Float16)W1[(size_t)(kk * 32 + kgrp * 8 + j) * 128 + col];
        bv[nt] = b1[col];
    }
    // W2 fragments: wave covers cols [wid*16, wid*16+16)
    half8 bf2[4];
    {
        int col = wid * 16 + lrow;
#pragma unroll
        for (int kk = 0; kk < 4; ++kk)
#pragma unroll
            for (int j = 0; j < 8; ++j)
                bf2[kk][j] = (_Float16)W2[(size_t)(kk * 32 + kgrp * 8 + j) * 64 + col];
    }

    const int m0 = blockIdx.x * 64;

    // ---- GEMM 1: acc1 = aggT @ W1 ----
    floatx4 acc1[4][2];
#pragma unroll
    for (int mt = 0; mt < 4; ++mt)
#pragma unroll
        for (int nt = 0; nt < 2; ++nt) acc1[mt][nt] = floatx4{0.f, 0.f, 0.f, 0.f};

#pragma unroll
    for (int kk = 0; kk < 4; ++kk) {
        const int k0 = kk * 32 + kgrp * 8;
        half8 af[4];
#pragma unroll
        for (int mt = 0; mt < 4; ++mt) {
            int row = m0 + mt * 16 + lrow;
            if (row >= n) row = n - 1;  // clamp; final stores guarded
            af[mt] = *reinterpret_cast<const half8*>(
                &aggT[(((size_t)(k0 >> 4)) * n + row) * 16 + (k0 & 15)]);
        }
#pragma unroll
        for (int mt = 0; mt < 4; ++mt)
#pragma unroll
            for (int nt = 0; nt < 2; ++nt)
                acc1[mt][nt] = __builtin_amdgcn_mfma_f32_16x16x32_f16(
                    af[mt], bf1[nt][kk], acc1[mt][nt], 0, 0, 0);
    }

    // ---- epilogue 1: relu(+b1) -> LDS fp16 tile ----
#pragma unroll
    for (int mt = 0; mt < 4; ++mt) {
#pragma unroll
        for (int r = 0; r < 4; ++r) {
            int rloc = mt * 16 + kgrp * 4 + r;
#pragma unroll
            for (int nt = 0; nt < 2; ++nt) {
                float v = fmaxf(acc1[mt][nt][r] + bv[nt], 0.0f);
                h1s[rloc][wid * 32 + nt * 16 + lrow] = (_Float16)v;
            }
        }
    }
    __syncthreads();

    // ---- GEMM 2: acc2 = h1 @ W2 ----
    floatx4 acc2[4];
#pragma unroll
    for (int mt = 0; mt < 4; ++mt) acc2[mt] = floatx4{0.f, 0.f, 0.f, 0.f};

#pragma unroll
    for (int kk = 0; kk < 4; ++kk) {
        const int k0 = kk * 32 + kgrp * 8;
#pragma unroll
        for (int mt = 0; mt < 4; ++mt) {
            half8 af = *reinterpret_cast<const half8*>(&h1s[mt * 16 + lrow][k0]);
            acc2[mt] = __builtin_amdgcn_mfma_f32_16x16x32_f16(
                af, bf2[kk], acc2[mt], 0, 0, 0);
        }
    }

    // ---- epilogue 2: *dinv -> thT slice-major [4][N+1][16] ----
#pragma unroll
    for (int mt = 0; mt < 4; ++mt) {
#pragma unroll
        for (int r = 0; r < 4; ++r) {
            int row = m0 + mt * 16 + kgrp * 4 + r;
            if (row < n) {
                float v = acc2[mt][r] * dinv[row];
                thT[((size_t)wid * (n + 1) + row) * 16 + lrow] = __float2half(v);
            }
        }
    }
}

// ---------------------------------------------------------------------------

extern "C" void kernel_launch(void* const* d_in, const int* in_sizes, int n_in,
                              void* d_out, int out_size, void* d_ws, size_t ws_size,
                              hipStream_t stream) {
    const float* x   = (const float*)d_in[0];
    const int*   ei  = (const int*)d_in[1];
    const float* W1  = (const float*)d_in[2];
    const float* b1  = (const float*)d_in[3];
    const float* W2  = (const float*)d_in[4];
    const float* b2  = (const float*)d_in[5];
    float*       out = (float*)d_out;

    const int N = in_sizes[0] / 128;
    const int E = in_sizes[1] / 2;
    const int* srcp = ei;      // edge_index[0]
    const int* dstp = ei + E;  // edge_index[1]

    const int nb   = (N + NT - 1) / NT;
    const int EPAD = E + 8 * N + 64;  // >= sum(padded degrees) + tail slack

    // workspace (512B-aligned):
    //   dinv[N] | cnt[N] | pdeg[N] | rowptr[N] | bsum[nb] | srcs[EPAD]
    //   | regA: xhT[8][N+1][16] fp16   | regB: aggT[8][N][16] fp16
    //   | regC: thT[4][N+1][16] fp16
    char* ws = (char*)d_ws;
    size_t off = 0;
    auto alloc = [&](size_t bytes) {
        char* p = ws + off;
        off = (off + bytes + 511) & ~(size_t)511;
        return p;
    };
    float*  dinv   = (float*)alloc((size_t)N * 4);
    int*    cnt    = (int*)alloc((size_t)N * 4);   // counts, then scatter cursor
    int*    pdeg   = (int*)alloc((size_t)N * 4);
    int*    rowptr = (int*)alloc((size_t)N * 4);
    int*    bsum   = (int*)alloc((size_t)nb * 4);
    int*    srcs   = (int*)alloc((size_t)EPAD * 4);
    __half* regA   = (__half*)alloc((size_t)(N + 1) * 128 * 2);   // xhT
    __half* regB   = (__half*)alloc((size_t)N * 128 * 2);         // aggT
    __half* regC   = (__half*)alloc((size_t)(N + 1) * 64 * 2);    // thT

    // ---- padded CSR build + norm ----
    zero_cnt_k<<<nb, NT, 0, stream>>>(cnt, N);
    deg_count_k<<<(E + NT - 1) / NT, NT, 0, stream>>>(dstp, cnt, E);
    scan1_k<<<nb, NT, 0, stream>>>(cnt, rowptr, bsum, dinv, pdeg, N);
    scan2_k<<<1, 512, 0, stream>>>(bsum, nb);
    scan3_k<<<nb, NT, 0, stream>>>(rowptr, bsum, cnt, N);
    {
        const int CH  = 2048;
        const int csz = (E + CH - 1) / CH;
        const int rpx = (N + 7) / 8;
        scatter_xcd_k<<<8 * CH, NT, 0, stream>>>(srcp, dstp, cnt, srcs, E, rpx, csz);
    }
    fill_pads_k<<<nb, NT, 0, stream>>>(cnt, rowptr, pdeg, srcs, N);

    // ---- layer 1: xhT (dummy row zeroed) -> aggT ----
    conv1T_k<<<((N + 1) * 8 + NT - 1) / NT, NT, 0, stream>>>(x, dinv, regA, N);
    gatherT128_k<<<((N + 31) / 32) * 8, NT, 0, stream>>>(
        rowptr, pdeg, srcs, dinv, regA, (__half2*)regB, N);

    // ---- fused MLP: aggT -> thT (relu(aggT@W1+b1)@W2)*dinv ----
    mgemm_fused_k<<<(N + 63) / 64, NT, 0, stream>>>(
        regB, W1, b1, W2, dinv, regC, N);

    // ---- layer 2 gather -> out (+b2) ----
    gatherT64_k<<<((N + 63) / 64) * 8, NT, 0, stream>>>(
        rowptr, pdeg, srcs, dinv, regC, b2, out, N);
}

// Round 18
// 302.638 us; speedup vs baseline: 1.1145x; 1.0201x over previous
//
#include <hip/hip_runtime.h>
#include <hip/hip_fp16.h>

// ---------------------------------------------------------------------------
// 2-layer GCN (PyG GCNConv): deg^{-1/2} sym norm with self-loops.
// Round 18 = round 17 + PAIRED slices (64B/request gathers).
//   Evidence r11 vs r16: gather duration tracks L1 request count
//   (1.125 vs 1.25 req/edge-slice -> 74.7 vs 80.9us). Pairing 16-col slices
//   into 32-col regions lets one 16-lane group read an edge's 64B pair-row
//   in ONE request -> data requests halve. Working set 6.4MB/XCD thrashes
//   L2 into L3 (fully L3-resident) - pays latency, not requests.
//   - xhP[4][N+1][32] fp16 pair-slices; gatherT128: 4 groups x 16 lanes.
//   - aggT kept [8][N][16] (mgemm_fused reads unchanged).
//   - thP[2][N+1][32]; gatherT64: 2 pairs, writes 128B/group rows (+b2).
//   - mgemm_fused: aggT -(W1,b1,relu)-> LDS -(W2,*dinv)-> thP.
//   - Dummy-padded CSR (dummy index N -> zeroed payload row), fdot2 accum,
//     XCD-localized scatter, precise pad fill.
// ---------------------------------------------------------------------------

#define NT 256

typedef _Float16 half8 __attribute__((ext_vector_type(8)));
typedef _Float16 h2 __attribute__((ext_vector_type(2)));
typedef float floatx4 __attribute__((ext_vector_type(4)));

#if __has_builtin(__builtin_amdgcn_fdot2)
__device__ __forceinline__ float dot2f(h2 a, h2 b, float c) {
    return __builtin_amdgcn_fdot2(a, b, c, false);
}
#else
__device__ __forceinline__ float dot2f(h2 a, h2 b, float c) {
    return c + (float)a.x * (float)b.x + (float)a.y * (float)b.y;
}
#endif

// ---------------- CSR build ----------------

__global__ void zero_cnt_k(int* __restrict__ cnt, int n) {
    int i = blockIdx.x * NT + threadIdx.x;
    if (i < n) cnt[i] = 0;
}

__global__ void deg_count_k(const int* __restrict__ dst, int* __restrict__ c, int e) {
    int i = blockIdx.x * NT + threadIdx.x;
    if (i < e) atomicAdd(&c[dst[i]], 1);
}

// exclusive scan of PADDED counts -> rowptr; emits dinv, pdeg
__global__ void scan1_k(const int* __restrict__ counts, int* __restrict__ rowptr,
                        int* __restrict__ bsum, float* __restrict__ dinv,
                        int* __restrict__ pdeg, int n) {
    __shared__ int s[NT];
    int tid = threadIdx.x, i = blockIdx.x * NT + tid;
    int v = (i < n) ? counts[i] : 0;
    int pv = (v + 7) & ~7;
    if (i < n) {
        dinv[i] = rsqrtf((float)(v + 1));  // +1 self-loop
        pdeg[i] = pv;
    }
    s[tid] = pv;
    __syncthreads();
    for (int off = 1; off < NT; off <<= 1) {
        int t = (tid >= off) ? s[tid - off] : 0;
        __syncthreads();
        if (tid >= off) s[tid] += t;
        __syncthreads();
    }
    if (i < n) rowptr[i] = s[tid] - pv;
    if (tid == NT - 1) bsum[blockIdx.x] = s[tid];
}

__global__ void scan2_k(int* __restrict__ bsum, int nb) {
    __shared__ int s[512];
    __shared__ int carry;
    int tid = threadIdx.x;
    if (tid == 0) carry = 0;
    __syncthreads();
    for (int base = 0; base < nb; base += 512) {
        int i = base + tid;
        int v = (i < nb) ? bsum[i] : 0;
        s[tid] = v;
        __syncthreads();
        for (int off = 1; off < 512; off <<= 1) {
            int t = (tid >= off) ? s[tid - off] : 0;
            __syncthreads();
            if (tid >= off) s[tid] += t;
            __syncthreads();
        }
        int tot = s[511];
        if (i < nb) bsum[i] = s[tid] - v + carry;
        __syncthreads();
        if (tid == 0) carry += tot;
        __syncthreads();
    }
}

__global__ void scan3_k(int* __restrict__ rowptr, const int* __restrict__ bsum,
                        int* __restrict__ cursor, int n) {
    int i = blockIdx.x * NT + threadIdx.x;
    if (i < n) {
        int r = rowptr[i] + bsum[i / NT];
        rowptr[i] = r;
        cursor[i] = r;
    }
}

// XCD-localized scatter (round 5)
__global__ __launch_bounds__(NT) void scatter_xcd_k(
    const int* __restrict__ src, const int* __restrict__ dst,
    int* __restrict__ cursor, int* __restrict__ srcs,
    int e, int rpx, int csz) {
    int q  = blockIdx.x & 7;
    int ch = blockIdx.x >> 3;
    int lo = q * rpx, hi = lo + rpx;
    int e0 = ch * csz;
    int e1 = min(e, e0 + csz);
    for (int i = e0 + (int)threadIdx.x; i < e1; i += NT) {
        int d = dst[i];
        if (d >= lo && d < hi) {
            int pos = atomicAdd(&cursor[d], 1);
            srcs[pos] = src[i];
        }
    }
}

// precise pad fill: fill [cursor[i], rowptr[i]+pdeg[i]) with dummy N;
// last node adds +8 slack for the unconditional one-batch-ahead prefetch.
__global__ void fill_pads_k(const int* __restrict__ cursor,
                            const int* __restrict__ rowptr,
                            const int* __restrict__ pdeg,
                            int* __restrict__ srcs, int n) {
    int i = blockIdx.x * NT + threadIdx.x;
    if (i >= n) return;
    int e  = cursor[i];
    int e1 = rowptr[i] + pdeg[i];
    for (; e < e1; ++e) srcs[e] = n;
    if (i == n - 1) {
#pragma unroll
        for (int j = 0; j < 8; ++j) srcs[e1 + j] = n;
    }
}

// ---------------- conv1T: x -> xhP[4][N+1][32] fp16 (row N zeroed) ---------
// thread t: node = t>>3, q = t&7 (16-col chunk); pair = q>>1, half = q&1.
__global__ void conv1T_k(const float* __restrict__ x, const float* __restrict__ dinv,
                         __half* __restrict__ xhP, int n) {
    int t = blockIdx.x * NT + threadIdx.x;
    int node = t >> 3;
    if (node > n) return;
    int q = t & 7;
    int4 o0, o1;
    if (node == n) {
        o0 = make_int4(0, 0, 0, 0);
        o1 = o0;
    } else {
        float dn = dinv[node];
        const float4* xp =
            reinterpret_cast<const float4*>(x + (size_t)node * 128 + q * 16);
        __half2 h[8];
#pragma unroll
        for (int j = 0; j < 4; ++j) {
            float4 a = xp[j];
            h[2 * j + 0] = __floats2half2_rn(a.x * dn, a.y * dn);
            h[2 * j + 1] = __floats2half2_rn(a.z * dn, a.w * dn);
        }
        o0 = reinterpret_cast<int4*>(h)[0];
        o1 = reinterpret_cast<int4*>(h)[1];
    }
    int4* op = reinterpret_cast<int4*>(
        xhP + ((size_t)(q >> 1) * (n + 1) + node) * 32 + (q & 1) * 16);
    op[0] = o0;
    op[1] = o1;
}

// ---------------- paired gathers: groups of 16 lanes, 64B/edge requests ----
// xhP/thP: [pair][N+1][32] fp16 -> 64 B per node per pair; row N zeros.
// Per 8-edge batch per group: index lanes (c&7) read one 32B segment
// (both halves coalesce), 8 shfl broadcasts, 8 x 64B full-row loads
// (ONE request each), 16 fdot2/lane. No masks, no ballots.

__global__ __launch_bounds__(NT) void gatherT128_k(
    const int* __restrict__ rowptr, const int* __restrict__ pdeg,
    const int* __restrict__ srcs, const float* __restrict__ dinv,
    const __half* __restrict__ xhP, __half2* __restrict__ aggT, int n) {
    const int q8    = blockIdx.x & 7;   // (pair, node-16-block parity)
    const int pair  = q8 & 3;
    const int chunk = blockIdx.x >> 3;
    const int lane  = threadIdx.x & 63;
    const int wid   = threadIdx.x >> 6;
    const int g     = lane >> 4;   // node sub-group 0..3
    const int c     = lane & 15;   // half2 col within 32-col pair
    const int node  = chunk * 32 + (q8 >> 2) * 16 + wid * 4 + g;
    if (node >= n) return;  // uniform within each 16-lane group

    const int e0 = rowptr[node];
    const int pd = pdeg[node];
    const char* base = (const char*)(xhP + (size_t)pair * (n + 1) * 32);
    const unsigned c4 = (unsigned)c * 4u;
    const h2 b10 = {(_Float16)1.0f, (_Float16)0.0f};
    const h2 b01 = {(_Float16)0.0f, (_Float16)1.0f};

    // self-loop (64 B row)
    h2 fs = *(const h2*)(base + (size_t)node * 64 + c4);
    float ax = dot2f(fs, b10, 0.0f);
    float ay = dot2f(fs, b01, 0.0f);

    int sidx = srcs[e0 + (c & 7)];
    for (int jb = 0; jb < pd; jb += 8) {
        int snext = srcs[e0 + jb + 8 + (c & 7)];  // padded buffer
#pragma unroll
        for (int u = 0; u < 8; ++u) {
            int s = __shfl(sidx, (lane & 0x30) | u, 64);
            h2 f = *(const h2*)(base + (unsigned)s * 64u + c4);
            ax = dot2f(f, b10, ax);
            ay = dot2f(f, b01, ay);
        }
        sidx = snext;
    }

    float dn = dinv[node];
    // aggT stays [8][N][16]: slice = pair*2 + (c>=8)
    int sl = pair * 2 + (c >> 3);
    aggT[((size_t)sl * n + node) * 8 + (c & 7)] =
        __floats2half2_rn(ax * dn, ay * dn);
}

// gatherT64: thP[2][N+1][32]; q8 -> (pair = q8&1, node-16-block offset q8>>1).
// Writes row-major fp32 out (+b2): group writes 128B contiguous.
__global__ __launch_bounds__(NT) void gatherT64_k(
    const int* __restrict__ rowptr, const int* __restrict__ pdeg,
    const int* __restrict__ srcs, const float* __restrict__ dinv,
    const __half* __restrict__ thP, const float* __restrict__ b2,
    float* __restrict__ out, int n) {
    const int q8    = blockIdx.x & 7;
    const int pair  = q8 & 1;
    const int chunk = blockIdx.x >> 3;
    const int lane  = threadIdx.x & 63;
    const int wid   = threadIdx.x >> 6;
    const int g     = lane >> 4;
    const int c     = lane & 15;
    const int node  = chunk * 64 + (q8 >> 1) * 16 + wid * 4 + g;
    if (node >= n) return;

    const int e0 = rowptr[node];
    const int pd = pdeg[node];
    const char* base = (const char*)(thP + (size_t)pair * (n + 1) * 32);
    const unsigned c4 = (unsigned)c * 4u;
    const h2 b10 = {(_Float16)1.0f, (_Float16)0.0f};
    const h2 b01 = {(_Float16)0.0f, (_Float16)1.0f};

    h2 fs = *(const h2*)(base + (size_t)node * 64 + c4);
    float ax = dot2f(fs, b10, 0.0f);
    float ay = dot2f(fs, b01, 0.0f);

    int sidx = srcs[e0 + (c & 7)];
    for (int jb = 0; jb < pd; jb += 8) {
        int snext = srcs[e0 + jb + 8 + (c & 7)];
#pragma unroll
        for (int u = 0; u < 8; ++u) {
            int s = __shfl(sidx, (lane & 0x30) | u, 64);
            h2 f = *(const h2*)(base + (unsigned)s * 64u + c4);
            ax = dot2f(f, b10, ax);
            ay = dot2f(f, b01, ay);
        }
        sidx = snext;
    }

    float dn = dinv[node];
    int col = pair * 32 + c * 2;
    *reinterpret_cast<float2*>(&out[(size_t)node * 64 + col]) =
        make_float2(ax * dn + b2[col], ay * dn + b2[col + 1]);
}

// ---------------- fused MLP: thP = (relu(aggT@W1 + b1) @ W2) * dinv --------
// MFMA fp16, register-resident W1/W2; h1 tile in LDS [64][136] (2-way free).
__global__ __launch_bounds__(NT) void mgemm_fused_k(
    const __half* __restrict__ aggT, const float* __restrict__ W1,
    const float* __restrict__ b1, const float* __restrict__ W2,
    const float* __restrict__ dinv, __half* __restrict__ thP, int n) {
    __shared__ _Float16 h1s[64][136];

    const int wid  = threadIdx.x >> 6;
    const int lane = threadIdx.x & 63;
    const int lrow = lane & 15;
    const int kgrp = lane >> 4;

    if (blockIdx.x == 0 && threadIdx.x < 64) {
        int pr = threadIdx.x >> 5, j = threadIdx.x & 31;
        thP[((size_t)pr * (n + 1) + n) * 32 + j] = __float2half(0.0f);
    }

    // W1 fragments: wave covers cols [wid*32, wid*32+32)
    half8 bf1[2][4];
    float bv[2];
#pragma unroll
    for (int nt = 0; nt < 2; ++nt) {
        int col = wid * 32 + nt * 16 + lrow;
#pragma unroll
        for (int kk = 0; kk < 4; ++kk)
#pragma unroll
            for (int j = 0; j < 8; ++j)
                bf1[nt][kk][j] = (_Float16)W1[(size_t)(kk * 32 + kgrp * 8 + j) * 128 + col];
        bv[nt] = b1[col];
    }
    // W2 fragments: wave covers cols [wid*16, wid*16+16)
    half8 bf2[4];
    {
        int col = wid * 16 + lrow;
#pragma unroll
        for (int kk = 0; kk < 4; ++kk)
#pragma unroll
            for (int j = 0; j < 8; ++j)
                bf2[kk][j] = (_Float16)W2[(size_t)(kk * 32 + kgrp * 8 + j) * 64 + col];
    }

    const int m0 = blockIdx.x * 64;

    // ---- GEMM 1: acc1 = aggT @ W1 ----
    floatx4 acc1[4][2];
#pragma unroll
    for (int mt = 0; mt < 4; ++mt)
#pragma unroll
        for (int nt = 0; nt < 2; ++nt) acc1[mt][nt] = floatx4{0.f, 0.f, 0.f, 0.f};

#pragma unroll
    for (int kk = 0; kk < 4; ++kk) {
        const int k0 = kk * 32 + kgrp * 8;
        half8 af[4];
#pragma unroll
        for (int mt = 0; mt < 4; ++mt) {
            int row = m0 + mt * 16 + lrow;
            if (row >= n) row = n - 1;  // clamp; final stores guarded
            af[mt] = *reinterpret_cast<const half8*>(
                &aggT[(((size_t)(k0 >> 4)) * n + row) * 16 + (k0 & 15)]);
        }
#pragma unroll
        for (int mt = 0; mt < 4; ++mt)
#pragma unroll
            for (int nt = 0; nt < 2; ++nt)
                acc1[mt][nt] = __builtin_amdgcn_mfma_f32_16x16x32_f16(
                    af[mt], bf1[nt][kk], acc1[mt][nt], 0, 0, 0);
    }

    // ---- epilogue 1: relu(+b1) -> LDS fp16 tile ----
#pragma unroll
    for (int mt = 0; mt < 4; ++mt) {
#pragma unroll
        for (int r = 0; r < 4; ++r) {
            int rloc = mt * 16 + kgrp * 4 + r;
#pragma unroll
            for (int nt = 0; nt < 2; ++nt) {
                float v = fmaxf(acc1[mt][nt][r] + bv[nt], 0.0f);
                h1s[rloc][wid * 32 + nt * 16 + lrow] = (_Float16)v;
            }
        }
    }
    __syncthreads();

    // ---- GEMM 2: acc2 = h1 @ W2 ----
    floatx4 acc2[4];
#pragma unroll
    for (int mt = 0; mt < 4; ++mt) acc2[mt] = floatx4{0.f, 0.f, 0.f, 0.f};

#pragma unroll
    for (int kk = 0; kk < 4; ++kk) {
        const int k0 = kk * 32 + kgrp * 8;
#pragma unroll
        for (int mt = 0; mt < 4; ++mt) {
            half8 af = *reinterpret_cast<const half8*>(&h1s[mt * 16 + lrow][k0]);
            acc2[mt] = __builtin_amdgcn_mfma_f32_16x16x32_f16(
                af, bf2[kk], acc2[mt], 0, 0, 0);
        }
    }

    // ---- epilogue 2: *dinv -> thP [2][N+1][32] ----
#pragma unroll
    for (int mt = 0; mt < 4; ++mt) {
#pragma unroll
        for (int r = 0; r < 4; ++r) {
            int row = m0 + mt * 16 + kgrp * 4 + r;
            if (row < n) {
                float v = acc2[mt][r] * dinv[row];
                int col = wid * 16 + lrow;
                thP[((size_t)(col >> 5) * (n + 1) + row) * 32 + (col & 31)] =
                    __float2half(v);
            }
        }
    }
}

// ---------------------------------------------------------------------------

extern "C" void kernel_launch(void* const* d_in, const int* in_sizes, int n_in,
                              void* d_out, int out_size, void* d_ws, size_t ws_size,
                              hipStream_t stream) {
    const float* x   = (const float*)d_in[0];
    const int*   ei  = (const int*)d_in[1];
    const float* W1  = (const float*)d_in[2];
    const float* b1  = (const float*)d_in[3];
    const float* W2  = (const float*)d_in[4];
    const float* b2  = (const float*)d_in[5];
    float*       out = (float*)d_out;

    const int N = in_sizes[0] / 128;
    const int E = in_sizes[1] / 2;
    const int* srcp = ei;      // edge_index[0]
    const int* dstp = ei + E;  // edge_index[1]

    const int nb   = (N + NT - 1) / NT;
    const int EPAD = E + 8 * N + 64;  // >= sum(padded degrees) + tail slack

    // workspace (512B-aligned):
    //   dinv[N] | cnt[N] | pdeg[N] | rowptr[N] | bsum[nb] | srcs[EPAD]
    //   | xhP[4][N+1][32] fp16 | aggT[8][N][16] fp16 | thP[2][N+1][32] fp16
    char* ws = (char*)d_ws;
    size_t off = 0;
    auto alloc = [&](size_t bytes) {
        char* p = ws + off;
        off = (off + bytes + 511) & ~(size_t)511;
        return p;
    };
    float*  dinv   = (float*)alloc((size_t)N * 4);
    int*    cnt    = (int*)alloc((size_t)N * 4);   // counts, then scatter cursor
    int*    pdeg   = (int*)alloc((size_t)N * 4);
    int*    rowptr = (int*)alloc((size_t)N * 4);
    int*    bsum   = (int*)alloc((size_t)nb * 4);
    int*    srcs   = (int*)alloc((size_t)EPAD * 4);
    __half* xhP    = (__half*)alloc((size_t)(N + 1) * 128 * 2);
    __half* aggT   = (__half*)alloc((size_t)N * 128 * 2);
    __half* thP    = (__half*)alloc((size_t)(N + 1) * 64 * 2);

    // ---- padded CSR build + norm ----
    zero_cnt_k<<<nb, NT, 0, stream>>>(cnt, N);
    deg_count_k<<<(E + NT - 1) / NT, NT, 0, stream>>>(dstp, cnt, E);
    scan1_k<<<nb, NT, 0, stream>>>(cnt, rowptr, bsum, dinv, pdeg, N);
    scan2_k<<<1, 512, 0, stream>>>(bsum, nb);
    scan3_k<<<nb, NT, 0, stream>>>(rowptr, bsum, cnt, N);
    {
        const int CH  = 2048;
        const int csz = (E + CH - 1) / CH;
        const int rpx = (N + 7) / 8;
        scatter_xcd_k<<<8 * CH, NT, 0, stream>>>(srcp, dstp, cnt, srcs, E, rpx, csz);
    }
    fill_pads_k<<<nb, NT, 0, stream>>>(cnt, rowptr, pdeg, srcs, N);

    // ---- layer 1: xhP (dummy row zeroed) -> aggT ----
    conv1T_k<<<((N + 1) * 8 + NT - 1) / NT, NT, 0, stream>>>(x, dinv, xhP, N);
    gatherT128_k<<<((N + 31) / 32) * 8, NT, 0, stream>>>(
        rowptr, pdeg, srcs, dinv, xhP, (__half2*)aggT, N);

    // ---- fused MLP: aggT -> thP = (relu(aggT@W1+b1)@W2)*dinv ----
    mgemm_fused_k<<<(N + 63) / 64, NT, 0, stream>>>(
        aggT, W1, b1, W2, dinv, thP, N);

    // ---- layer 2 gather -> out (+b2) ----
    gatherT64_k<<<((N + 63) / 64) * 8, NT, 0, stream>>>(
        rowptr, pdeg, srcs, dinv, thP, b2, out, N);
}